// Round 17
// baseline (169.876 us; speedup 1.0000x reference)
//
#include <hip/hip_runtime.h>
#include <hip/hip_bf16.h>

// GRU cell v17: v16 structure (32x32x16 MFMA, wave tile 64x64, 4 waves/256 thr,
// 64-row tiles, 64 KB LDS, 2 blocks/CU, (256,2) -> 256-reg budget, z in regs,
// rh parked in h_l, 3 barriers) with ONE change: sweep32 is the naive per-chunk
// form (direct loads, no manual rings, NO sched_barrier fences). At a 256-reg
// budget the LLVM scheduler software-pipelines to its own depth -- ablating
// whether v16's hand pipeline was helping or pinning the schedule.

typedef __attribute__((ext_vector_type(8)))  short s8v;            // 8 bf16 = 4 VGPR
typedef __attribute__((ext_vector_type(8)))  unsigned short us8;
typedef __attribute__((ext_vector_type(16))) float f16v;           // 32x32 acc tile
typedef __attribute__((ext_vector_type(4)))  float f4v;

__device__ __forceinline__ float bf2f(unsigned short u) {
  union { unsigned int i; float f; } c; c.i = ((unsigned int)u) << 16; return c.f;
}
__device__ __forceinline__ unsigned short f2bf(float f) {
  __hip_bfloat16 b = __float2bfloat16(f);            // RNE, pairs into v_cvt_pk_bf16_f32
  union { __hip_bfloat16 b; unsigned short u; } c; c.b = b; return c.u;
}
__device__ __forceinline__ unsigned int pk2(float lo, float hi) {
  return (unsigned int)f2bf(lo) | ((unsigned int)f2bf(hi) << 16);
}
__device__ __forceinline__ float sig_(float s)  { return 1.0f / (1.0f + __expf(-s)); }
__device__ __forceinline__ float tanh_(float s) { return 2.0f / (1.0f + __expf(-2.0f * s)) - 1.0f; }

// ---------------- weight prep: fp32 [K][N] -> bf16 32-col fragment tiles ----------------
// Tile (nt, kt) = 32 n x 16 k = 512 shorts (1 KB), lane-major:
//   n = nt*32 + (lane&31), k = kt*16 + (lane>>5)*8 + e ; tile index t = nt*32 + kt.
// wzr: nt 0..7 = Wz/Uz, nt 8..15 = Wr/Ur. whh: nt 0..7 = Wh/Uh. k<256 -> W, else U.
__global__ void gru_prep(const float* __restrict__ Wz, const float* __restrict__ Uz,
                         const float* __restrict__ Wr, const float* __restrict__ Ur,
                         const float* __restrict__ Wh, const float* __restrict__ Uh,
                         unsigned short* __restrict__ wzr, unsigned short* __restrict__ whh) {
  int idx = blockIdx.x * 256 + threadIdx.x;
  if (idx < 512 * 512) {
    int t = idx >> 9, s = idx & 511, lane = s >> 3, e = s & 7;
    int nt = t >> 5, kt = t & 31;
    int n = nt * 32 + (lane & 31);
    int k = kt * 16 + ((lane >> 5) << 3) + e;
    int nn = n & 255;
    float v;
    if (n < 256) v = (k < 256) ? Wz[k * 256 + nn] : Uz[(k - 256) * 256 + nn];
    else         v = (k < 256) ? Wr[k * 256 + nn] : Ur[(k - 256) * 256 + nn];
    wzr[idx] = f2bf(v);
  } else if (idx < 512 * 512 + 256 * 512) {
    int j = idx - 512 * 512;
    int t = j >> 9, s = j & 511, lane = s >> 3, e = s & 7;
    int nt = t >> 5, kt = t & 31;
    int n = nt * 32 + (lane & 31);
    int k = kt * 16 + ((lane >> 5) << 3) + e;
    float v = (k < 256) ? Wh[k * 256 + n] : Uh[(k - 256) * 256 + n];
    whh[j] = f2bf(v);
  }
}

#define MFMA32(a, b, c) __builtin_amdgcn_mfma_f32_32x32x16_bf16((a), (b), (c), 0, 0, 0)

// ---- K=512 sweep: 32 chunks of 16; A = x_l (c<16) then h_l (c>=16) ----
// NAIVE form: direct loads per chunk, no fences, no manual rings.
// Fully unrolled; scheduler pipelines to the depth the 256-reg budget allows.
__device__ __forceinline__ void sweep32(f16v acc[2][2],
    const unsigned short* __restrict__ b0p, const unsigned short* __restrict__ b1p,
    const unsigned short* Ax, const unsigned short* Ah, int l31, int hi)
{
  const int r7 = l31 & 7;                    // rows l31 and 32+l31 share (row&7)
  const unsigned short* Ax0 = Ax + l31 * 256;
  const unsigned short* Ax1 = Ax + (32 + l31) * 256;
  const unsigned short* Ah0 = Ah + l31 * 256;
  const unsigned short* Ah1 = Ah + (32 + l31) * 256;
#pragma unroll
  for (int c = 0; c < 32; ++c) {
    const unsigned short* A0 = (c < 16) ? Ax0 : Ah0;
    const unsigned short* A1 = (c < 16) ? Ax1 : Ah1;
    const int kk = c & 15;
    const int gp = ((kk * 2 + hi) ^ r7) * 8;
    s8v a0  = *(const s8v*)(A0 + gp);
    s8v a1  = *(const s8v*)(A1 + gp);
    s8v bb0 = *(const s8v*)(b0p + c * 512);
    s8v bb1 = *(const s8v*)(b1p + c * 512);
    acc[0][0] = MFMA32(a0, bb0, acc[0][0]);
    acc[0][1] = MFMA32(a0, bb1, acc[0][1]);
    acc[1][0] = MFMA32(a1, bb0, acc[1][0]);
    acc[1][1] = MFMA32(a1, bb1, acc[1][1]);
  }
}

// swizzled scalar LDS accessors (granule-XOR layout)
__device__ __forceinline__ float ldsA_get(const unsigned short* A, int row, int col) {
  int gp = ((col >> 3) ^ (row & 7));
  return bf2f(A[row * 256 + gp * 8 + (col & 7)]);
}
__device__ __forceinline__ void ldsA_put(unsigned short* A, int row, int col, unsigned short v) {
  int gp = ((col >> 3) ^ (row & 7));
  A[row * 256 + gp * 8 + (col & 7)] = v;
}

// C-tile row for reg q (m74/m101 verified): (q&3) + 8*(q>>2) + 4*hi
#define CROW(q, hi) (((q) & 3) + 8 * ((q) >> 2) + 4 * (hi))

// ---------------- main fused kernel: 64 rows per block, 4 waves ----------------
__global__ __launch_bounds__(256, 2) void gru_main(
    const float* __restrict__ x, const float* __restrict__ hp,
    const unsigned short* __restrict__ wzr, const unsigned short* __restrict__ whh,
    const float* __restrict__ bz, const float* __restrict__ br, const float* __restrict__ bh,
    float* __restrict__ out)
{
  __shared__ __align__(16) unsigned short x_l[64 * 256];   // 32 KB; x (bf16, XOR layout)
  __shared__ __align__(16) unsigned short h_l[64 * 256];   // 32 KB; h_prev, later rh

  const int tid = threadIdx.x;
  const int lane = tid & 63;
  const int wv = tid >> 6;                   // 0..3 : wave's 64-col slice
  const int l31 = lane & 31, hi = lane >> 5;
  const int row0 = blockIdx.x * 64;

  // B tile streams (nt stride 16384 shorts = 32 chunks x 512); wave owns nt wv*2, wv*2+1
  const unsigned short* Bz = wzr + (size_t)(wv * 2) * 16384 + lane * 8;
  const unsigned short* Br = wzr + 131072 + (size_t)(wv * 2) * 16384 + lane * 8;
  const unsigned short* Bh = whh + (size_t)(wv * 2) * 16384 + lane * 8;

  // ---- stage x, h tiles to LDS (fp32 -> bf16), granule-XOR layout; 64 elems/thread/array
  {
    const int srow = tid >> 2;               // 0..63
    const int part = tid & 3;                // 64 cols = 8 granules each
    const float* xs = x  + (size_t)(row0 + srow) * 256 + part * 64;
    const float* hs = hp + (size_t)(row0 + srow) * 256 + part * 64;
    unsigned short* xd = x_l + srow * 256;
    unsigned short* hd = h_l + srow * 256;
    const int r7 = srow & 7;
#pragma unroll
    for (int j = 0; j < 8; ++j) {
      int gp = (part * 8 + j) ^ r7;
      f4v v0 = *(const f4v*)(xs + j * 8);
      f4v v1 = *(const f4v*)(xs + j * 8 + 4);
      us8 o;
      o[0]=f2bf(v0[0]); o[1]=f2bf(v0[1]); o[2]=f2bf(v0[2]); o[3]=f2bf(v0[3]);
      o[4]=f2bf(v1[0]); o[5]=f2bf(v1[1]); o[6]=f2bf(v1[2]); o[7]=f2bf(v1[3]);
      *(us8*)(xd + gp * 8) = o;
    }
#pragma unroll
    for (int j = 0; j < 8; ++j) {
      int gp = (part * 8 + j) ^ r7;
      f4v v0 = *(const f4v*)(hs + j * 8);
      f4v v1 = *(const f4v*)(hs + j * 8 + 4);
      us8 o;
      o[0]=f2bf(v0[0]); o[1]=f2bf(v0[1]); o[2]=f2bf(v0[2]); o[3]=f2bf(v0[3]);
      o[4]=f2bf(v1[0]); o[5]=f2bf(v1[1]); o[6]=f2bf(v1[2]); o[7]=f2bf(v1[3]);
      *(us8*)(hd + gp * 8) = o;
    }
  }
  __syncthreads();                           // B1

  f16v acc[2][2];
  unsigned int zp[2][2][8];                  // z gate, packed bf16 : 32 VGPR

  // ===== PASS z: z = sigmoid(x Wz + h Uz + bz) -> zp (registers)
  acc[0][0] = (f16v)(0.f); acc[0][1] = (f16v)(0.f);
  acc[1][0] = (f16v)(0.f); acc[1][1] = (f16v)(0.f);
  sweep32(acc, Bz, Bz + 16384, x_l, h_l, l31, hi);
#pragma unroll
  for (int fa = 0; fa < 2; ++fa)
#pragma unroll
    for (int fb = 0; fb < 2; ++fb) {
      const int col = wv * 64 + fb * 32 + l31;
      const float bv = bz[col];
#pragma unroll
      for (int qq = 0; qq < 8; ++qq) {
        const int q0 = 2 * qq;
        zp[fa][fb][qq] = pk2(sig_(acc[fa][fb][q0] + bv), sig_(acc[fa][fb][q0 + 1] + bv));
      }
    }

  // ===== PASS r: r = sigmoid(x Wr + h Ur + br); rh = r * h_prev -> parked in h_l
  acc[0][0] = (f16v)(0.f); acc[0][1] = (f16v)(0.f);
  acc[1][0] = (f16v)(0.f); acc[1][1] = (f16v)(0.f);
  sweep32(acc, Br, Br + 16384, x_l, h_l, l31, hi);
  {
    unsigned int rhp[2][2][8];               // transient 32 VGPR (spans one barrier)
#pragma unroll
    for (int fa = 0; fa < 2; ++fa)
#pragma unroll
      for (int fb = 0; fb < 2; ++fb) {
        const int col = wv * 64 + fb * 32 + l31;
        const float bv = br[col];
#pragma unroll
        for (int qq = 0; qq < 8; ++qq) {
          const int q0 = 2 * qq;
          const int r0 = fa * 32 + CROW(q0, hi);
          const float rr0 = sig_(acc[fa][fb][q0]     + bv) * ldsA_get(h_l, r0,     col);
          const float rr1 = sig_(acc[fa][fb][q0 + 1] + bv) * ldsA_get(h_l, r0 + 1, col);
          rhp[fa][fb][qq] = pk2(rr0, rr1);
        }
      }
    __syncthreads();                         // B2: all z/r GEMM + epilogue reads of h_l done
#pragma unroll
    for (int fa = 0; fa < 2; ++fa)
#pragma unroll
      for (int fb = 0; fb < 2; ++fb) {
        const int col = wv * 64 + fb * 32 + l31;
#pragma unroll
        for (int qq = 0; qq < 8; ++qq) {
          const int q0 = 2 * qq;
          const int r0 = fa * 32 + CROW(q0, hi);
          const unsigned int w = rhp[fa][fb][qq];
          ldsA_put(h_l, r0,     col, (unsigned short)(w & 0xffffu));
          ldsA_put(h_l, r0 + 1, col, (unsigned short)(w >> 16));
        }
      }
  }
  __syncthreads();                           // B3: rh visible to all waves

  // ===== PASS h: h_hat = tanh(x Wh + rh Uh + bh); h_l now holds rh
  acc[0][0] = (f16v)(0.f); acc[0][1] = (f16v)(0.f);
  acc[1][0] = (f16v)(0.f); acc[1][1] = (f16v)(0.f);
  sweep32(acc, Bh, Bh + 16384, x_l, h_l, l31, hi);

  // ===== final epilogue: h = z*h_prev + (1-z)*h_hat (z from regs, h_prev from global)
#pragma unroll
  for (int fa = 0; fa < 2; ++fa)
#pragma unroll
    for (int fb = 0; fb < 2; ++fb) {
      const int col = wv * 64 + fb * 32 + l31;
      const float bv = bh[col];
#pragma unroll
      for (int qq = 0; qq < 8; ++qq) {
        const int q0 = 2 * qq;
        const int r0 = fa * 32 + CROW(q0, hi);
        const unsigned int zw = zp[fa][fb][qq];
#pragma unroll
        for (int j = 0; j < 2; ++j) {
          const int row = r0 + j;
          const size_t oi = (size_t)(row0 + row) * 256 + col;
          const float hh = tanh_(acc[fa][fb][q0 + j] + bv);
          const float z = bf2f((unsigned short)(j ? (zw >> 16) : (zw & 0xffffu)));
          out[oi] = z * hp[oi] + (1.0f - z) * hh;
        }
      }
    }
}

extern "C" void kernel_launch(void* const* d_in, const int* in_sizes, int n_in,
                              void* d_out, int out_size, void* d_ws, size_t ws_size,
                              hipStream_t stream) {
  const float* x  = (const float*)d_in[0];
  const float* hp = (const float*)d_in[1];
  const float* Wz = (const float*)d_in[2];
  const float* Uz = (const float*)d_in[3];
  const float* bz = (const float*)d_in[4];
  const float* Wr = (const float*)d_in[5];
  const float* Ur = (const float*)d_in[6];
  const float* br = (const float*)d_in[7];
  const float* Wh = (const float*)d_in[8];
  const float* Uh = (const float*)d_in[9];
  const float* bh = (const float*)d_in[10];

  if (ws_size < (size_t)(512 * 512 + 256 * 512) * sizeof(unsigned short)) return;  // need 768 KB

  unsigned short* wzr = (unsigned short*)d_ws;
  unsigned short* whh = wzr + 512 * 512;

  gru_prep<<<1536, 256, 0, stream>>>(Wz, Uz, Wr, Ur, Wh, Uh, wzr, whh);
  gru_main<<<1024, 256, 0, stream>>>(x, hp, wzr, whh, bz, br, bh, (float*)d_out);
}

// Round 18
// 125.860 us; speedup vs baseline: 1.3497x; 1.3497x over previous
//
#include <hip/hip_runtime.h>
#include <hip/hip_bf16.h>

// GRU cell v18: v16's fenced ring pipeline at DOUBLE occupancy.
// 32-row tiles, 2048 blocks x 256 thr, wave tile 32x64 (acc = 2x16 = 32 AGPR),
// LDS 32 KB -> 4 blocks/CU, 4 waves/SIMD via launch_bounds(256,4) (128-reg
// budget; live set ~116 fits because z parks in d_out, v14-proven).
// B ring-5/distance-4 (2 streams), A ring-3/distance-2 (1 frag), sched_barrier
// fenced (v17 ablation: fences are mandatory). rh parks in h_l; 3 barriers.

typedef __attribute__((ext_vector_type(8)))  short s8v;            // 8 bf16 = 4 VGPR
typedef __attribute__((ext_vector_type(8)))  unsigned short us8;
typedef __attribute__((ext_vector_type(16))) float f16v;           // 32x32 acc tile
typedef __attribute__((ext_vector_type(4)))  float f4v;

__device__ __forceinline__ float bf2f(unsigned short u) {
  union { unsigned int i; float f; } c; c.i = ((unsigned int)u) << 16; return c.f;
}
__device__ __forceinline__ unsigned short f2bf(float f) {
  __hip_bfloat16 b = __float2bfloat16(f);            // RNE, pairs into v_cvt_pk_bf16_f32
  union { __hip_bfloat16 b; unsigned short u; } c; c.b = b; return c.u;
}
__device__ __forceinline__ unsigned int pk2(float lo, float hi) {
  return (unsigned int)f2bf(lo) | ((unsigned int)f2bf(hi) << 16);
}
__device__ __forceinline__ float sig_(float s)  { return 1.0f / (1.0f + __expf(-s)); }
__device__ __forceinline__ float tanh_(float s) { return 2.0f / (1.0f + __expf(-2.0f * s)) - 1.0f; }

// ---------------- weight prep: fp32 [K][N] -> bf16 32-col fragment tiles ----------------
// Tile (nt, kt) = 32 n x 16 k = 512 shorts (1 KB), lane-major:
//   n = nt*32 + (lane&31), k = kt*16 + (lane>>5)*8 + e ; tile index t = nt*32 + kt.
// wzr: nt 0..7 = Wz/Uz, nt 8..15 = Wr/Ur. whh: nt 0..7 = Wh/Uh. k<256 -> W, else U.
__global__ void gru_prep(const float* __restrict__ Wz, const float* __restrict__ Uz,
                         const float* __restrict__ Wr, const float* __restrict__ Ur,
                         const float* __restrict__ Wh, const float* __restrict__ Uh,
                         unsigned short* __restrict__ wzr, unsigned short* __restrict__ whh) {
  int idx = blockIdx.x * 256 + threadIdx.x;
  if (idx < 512 * 512) {
    int t = idx >> 9, s = idx & 511, lane = s >> 3, e = s & 7;
    int nt = t >> 5, kt = t & 31;
    int n = nt * 32 + (lane & 31);
    int k = kt * 16 + ((lane >> 5) << 3) + e;
    int nn = n & 255;
    float v;
    if (n < 256) v = (k < 256) ? Wz[k * 256 + nn] : Uz[(k - 256) * 256 + nn];
    else         v = (k < 256) ? Wr[k * 256 + nn] : Ur[(k - 256) * 256 + nn];
    wzr[idx] = f2bf(v);
  } else if (idx < 512 * 512 + 256 * 512) {
    int j = idx - 512 * 512;
    int t = j >> 9, s = j & 511, lane = s >> 3, e = s & 7;
    int nt = t >> 5, kt = t & 31;
    int n = nt * 32 + (lane & 31);
    int k = kt * 16 + ((lane >> 5) << 3) + e;
    float v = (k < 256) ? Wh[k * 256 + n] : Uh[(k - 256) * 256 + n];
    whh[j] = f2bf(v);
  }
}

#define MFMA32(a, b, c) __builtin_amdgcn_mfma_f32_32x32x16_bf16((a), (b), (c), 0, 0, 0)

// ---- K=512 sweep: 32 chunks of 16; A = x_l (c<16) then h_l (c>=16) ----
// 32x64 wave tile: 1 A-frag (rows 0..31 = l31) x 2 B-frags -> 2 MFMA/chunk.
// B: ring-5 distance-4 ; A: ring-3 distance-2. Static indices; fenced.
__device__ __forceinline__ void sweep32(f16v acc[2],
    const unsigned short* __restrict__ b0p, const unsigned short* __restrict__ b1p,
    const unsigned short* Ax, const unsigned short* Ah, int l31, int hi)
{
  const int r7 = l31 & 7;
  const unsigned short* Ax0 = Ax + l31 * 256;
  const unsigned short* Ah0 = Ah + l31 * 256;
  s8v b[5][2];
  s8v a[3];
#pragma unroll
  for (int i = 0; i < 4; ++i) {
    b[i][0] = *(const s8v*)(b0p + i * 512);
    b[i][1] = *(const s8v*)(b1p + i * 512);
  }
  a[0] = *(const s8v*)(Ax0 + ((0 + hi) ^ r7) * 8);
  a[1] = *(const s8v*)(Ax0 + ((2 + hi) ^ r7) * 8);
#pragma unroll
  for (int c = 0; c < 32; ++c) {
    if (c + 4 < 32) {
      const int s = (c + 4) % 5;
      b[s][0] = *(const s8v*)(b0p + (c + 4) * 512);
      b[s][1] = *(const s8v*)(b1p + (c + 4) * 512);
    }
    if (c + 2 < 32) {
      const int cn = c + 2;
      const int kk = cn & 15;
      const int gp = ((kk * 2 + hi) ^ r7) * 8;
      const int s = cn % 3;
      a[s] = (cn < 16) ? *(const s8v*)(Ax0 + gp) : *(const s8v*)(Ah0 + gp);
    }
    __builtin_amdgcn_sched_barrier(0);
    const int sb = c % 5, sa = c % 3;
    acc[0] = MFMA32(a[sa], b[sb][0], acc[0]);
    acc[1] = MFMA32(a[sa], b[sb][1], acc[1]);
    __builtin_amdgcn_sched_barrier(0);
  }
}

// swizzled scalar LDS accessors (granule-XOR layout)
__device__ __forceinline__ float ldsA_get(const unsigned short* A, int row, int col) {
  int gp = ((col >> 3) ^ (row & 7));
  return bf2f(A[row * 256 + gp * 8 + (col & 7)]);
}
__device__ __forceinline__ void ldsA_put(unsigned short* A, int row, int col, unsigned short v) {
  int gp = ((col >> 3) ^ (row & 7));
  A[row * 256 + gp * 8 + (col & 7)] = v;
}

// C-tile row for reg q (m74/m101 verified): (q&3) + 8*(q>>2) + 4*hi
#define CROW(q, hi) (((q) & 3) + 8 * ((q) >> 2) + 4 * (hi))

// ---------------- main fused kernel: 32 rows per block, 4 waves ----------------
__global__ __launch_bounds__(256, 4) void gru_main(
    const float* __restrict__ x, const float* __restrict__ hp,
    const unsigned short* __restrict__ wzr, const unsigned short* __restrict__ whh,
    const float* __restrict__ bz, const float* __restrict__ br, const float* __restrict__ bh,
    float* __restrict__ out)
{
  __shared__ __align__(16) unsigned short x_l[32 * 256];   // 16 KB; x (bf16, XOR layout)
  __shared__ __align__(16) unsigned short h_l[32 * 256];   // 16 KB; h_prev, later rh

  const int tid = threadIdx.x;
  const int lane = tid & 63;
  const int wv = tid >> 6;                   // 0..3 : wave's 64-col slice
  const int l31 = lane & 31, hi = lane >> 5;
  const int row0 = blockIdx.x * 32;

  // B tile streams (nt stride 16384 shorts = 32 chunks x 512); wave owns nt wv*2, wv*2+1
  const unsigned short* Bz = wzr + (size_t)(wv * 2) * 16384 + lane * 8;
  const unsigned short* Br = wzr + 131072 + (size_t)(wv * 2) * 16384 + lane * 8;
  const unsigned short* Bh = whh + (size_t)(wv * 2) * 16384 + lane * 8;

  unsigned int* outw = (unsigned int*)out;

  // ---- stage x, h tiles to LDS (fp32 -> bf16), granule-XOR layout; 32 elems/thread/array
  {
    const int srow = tid >> 3;               // 0..31
    const int part = tid & 7;                // 4 granules each
    const float* xs = x  + (size_t)(row0 + srow) * 256 + part * 32;
    const float* hs = hp + (size_t)(row0 + srow) * 256 + part * 32;
    unsigned short* xd = x_l + srow * 256;
    unsigned short* hd = h_l + srow * 256;
    const int r7 = srow & 7;
#pragma unroll
    for (int j = 0; j < 4; ++j) {
      int gp = (part * 4 + j) ^ r7;
      f4v v0 = *(const f4v*)(xs + j * 8);
      f4v v1 = *(const f4v*)(xs + j * 8 + 4);
      us8 o;
      o[0]=f2bf(v0[0]); o[1]=f2bf(v0[1]); o[2]=f2bf(v0[2]); o[3]=f2bf(v0[3]);
      o[4]=f2bf(v1[0]); o[5]=f2bf(v1[1]); o[6]=f2bf(v1[2]); o[7]=f2bf(v1[3]);
      *(us8*)(xd + gp * 8) = o;
    }
#pragma unroll
    for (int j = 0; j < 4; ++j) {
      int gp = (part * 4 + j) ^ r7;
      f4v v0 = *(const f4v*)(hs + j * 8);
      f4v v1 = *(const f4v*)(hs + j * 8 + 4);
      us8 o;
      o[0]=f2bf(v0[0]); o[1]=f2bf(v0[1]); o[2]=f2bf(v0[2]); o[3]=f2bf(v0[3]);
      o[4]=f2bf(v1[0]); o[5]=f2bf(v1[1]); o[6]=f2bf(v1[2]); o[7]=f2bf(v1[3]);
      *(us8*)(hd + gp * 8) = o;
    }
  }
  __syncthreads();                           // B1

  f16v acc[2];

  // ===== PASS z: z = sigmoid(x Wz + h Uz + bz) -> parked in d_out (thread-private dwords)
  acc[0] = (f16v)(0.f); acc[1] = (f16v)(0.f);
  sweep32(acc, Bz, Bz + 16384, x_l, h_l, l31, hi);
#pragma unroll
  for (int fb = 0; fb < 2; ++fb) {
    const int col = wv * 64 + fb * 32 + l31;
    const float bv = bz[col];
#pragma unroll
    for (int qq = 0; qq < 8; ++qq) {
      const int q0 = 2 * qq;
      const int r0 = CROW(q0, hi);
      outw[(size_t)(row0 + r0) * 256 + col] =
          pk2(sig_(acc[fb][q0] + bv), sig_(acc[fb][q0 + 1] + bv));
    }
  }

  // ===== PASS r: r = sigmoid(x Wr + h Ur + br); rh = r * h_prev -> parked in h_l
  acc[0] = (f16v)(0.f); acc[1] = (f16v)(0.f);
  sweep32(acc, Br, Br + 16384, x_l, h_l, l31, hi);
  {
    unsigned int rhp[2][8];                  // transient 16 VGPR (spans one barrier)
#pragma unroll
    for (int fb = 0; fb < 2; ++fb) {
      const int col = wv * 64 + fb * 32 + l31;
      const float bv = br[col];
#pragma unroll
      for (int qq = 0; qq < 8; ++qq) {
        const int q0 = 2 * qq;
        const int r0 = CROW(q0, hi);
        const float rr0 = sig_(acc[fb][q0]     + bv) * ldsA_get(h_l, r0,     col);
        const float rr1 = sig_(acc[fb][q0 + 1] + bv) * ldsA_get(h_l, r0 + 1, col);
        rhp[fb][qq] = pk2(rr0, rr1);
      }
    }
    __syncthreads();                         // B2: all z/r GEMM + epilogue reads of h_l done
#pragma unroll
    for (int fb = 0; fb < 2; ++fb) {
      const int col = wv * 64 + fb * 32 + l31;
#pragma unroll
      for (int qq = 0; qq < 8; ++qq) {
        const int q0 = 2 * qq;
        const int r0 = CROW(q0, hi);
        const unsigned int w = rhp[fb][qq];
        ldsA_put(h_l, r0,     col, (unsigned short)(w & 0xffffu));
        ldsA_put(h_l, r0 + 1, col, (unsigned short)(w >> 16));
      }
    }
  }
  __syncthreads();                           // B3: rh visible to all waves

  // ===== PASS h: h_hat = tanh(x Wh + rh Uh + bh); h_l now holds rh
  acc[0] = (f16v)(0.f); acc[1] = (f16v)(0.f);
  sweep32(acc, Bh, Bh + 16384, x_l, h_l, l31, hi);

  // ===== final epilogue: h = z*h_prev + (1-z)*h_hat (z from d_out, h_prev from global)
#pragma unroll
  for (int fb = 0; fb < 2; ++fb) {
    const int col = wv * 64 + fb * 32 + l31;
    const float bv = bh[col];
#pragma unroll
    for (int qq = 0; qq < 8; ++qq) {
      const int q0 = 2 * qq;
      const int r0 = CROW(q0, hi);
      const unsigned int zw = outw[(size_t)(row0 + r0) * 256 + col];
#pragma unroll
      for (int j = 0; j < 2; ++j) {
        const int row = r0 + j;
        const size_t oi = (size_t)(row0 + row) * 256 + col;
        const float hh = tanh_(acc[fb][q0 + j] + bv);
        const float z = bf2f((unsigned short)(j ? (zw >> 16) : (zw & 0xffffu)));
        out[oi] = z * hp[oi] + (1.0f - z) * hh;
      }
    }
  }
}

extern "C" void kernel_launch(void* const* d_in, const int* in_sizes, int n_in,
                              void* d_out, int out_size, void* d_ws, size_t ws_size,
                              hipStream_t stream) {
  const float* x  = (const float*)d_in[0];
  const float* hp = (const float*)d_in[1];
  const float* Wz = (const float*)d_in[2];
  const float* Uz = (const float*)d_in[3];
  const float* bz = (const float*)d_in[4];
  const float* Wr = (const float*)d_in[5];
  const float* Ur = (const float*)d_in[6];
  const float* br = (const float*)d_in[7];
  const float* Wh = (const float*)d_in[8];
  const float* Uh = (const float*)d_in[9];
  const float* bh = (const float*)d_in[10];

  if (ws_size < (size_t)(512 * 512 + 256 * 512) * sizeof(unsigned short)) return;  // need 768 KB

  unsigned short* wzr = (unsigned short*)d_ws;
  unsigned short* whh = wzr + 512 * 512;

  gru_prep<<<1536, 256, 0, stream>>>(Wz, Uz, Wr, Ur, Wh, Uh, wzr, whh);
  gru_main<<<2048, 256, 0, stream>>>(x, hp, wzr, whh, bz, br, bh, (float*)d_out);
}

// Round 19
// 114.377 us; speedup vs baseline: 1.4852x; 1.1004x over previous
//
#include <hip/hip_runtime.h>
#include <hip/hip_bf16.h>

// GRU cell v19: v16 structure (32x32x16 MFMA, wave tile 64x64, 4 waves/256 thr,
// 64-row tiles, 64 KB LDS, 2 blocks/CU, (256,2)) with z+r sweeps FUSED:
// one 32-chunk sweep computes both gates (8 MFMA/chunk, 4 independent acc
// chains, shared A-frags) -> chunk count 96->64, A-LDS reads halved for 2
// passes. accz+accr = 128 AGPR; arch live ~110 <= 128 quantum.
// z in regs after fused sweep; rh parks in h_l; 3 barriers; fenced rings
// (v17 ablation: fences mandatory). B ring-4/distance-3, A ring-3/distance-2.

typedef __attribute__((ext_vector_type(8)))  short s8v;            // 8 bf16 = 4 VGPR
typedef __attribute__((ext_vector_type(8)))  unsigned short us8;
typedef __attribute__((ext_vector_type(16))) float f16v;           // 32x32 acc tile
typedef __attribute__((ext_vector_type(4)))  float f4v;

__device__ __forceinline__ float bf2f(unsigned short u) {
  union { unsigned int i; float f; } c; c.i = ((unsigned int)u) << 16; return c.f;
}
__device__ __forceinline__ unsigned short f2bf(float f) {
  __hip_bfloat16 b = __float2bfloat16(f);            // RNE, pairs into v_cvt_pk_bf16_f32
  union { __hip_bfloat16 b; unsigned short u; } c; c.b = b; return c.u;
}
__device__ __forceinline__ unsigned int pk2(float lo, float hi) {
  return (unsigned int)f2bf(lo) | ((unsigned int)f2bf(hi) << 16);
}
__device__ __forceinline__ float sig_(float s)  { return 1.0f / (1.0f + __expf(-s)); }
__device__ __forceinline__ float tanh_(float s) { return 2.0f / (1.0f + __expf(-2.0f * s)) - 1.0f; }

// ---------------- weight prep: fp32 [K][N] -> bf16 32-col fragment tiles ----------------
// Tile (nt, kt) = 32 n x 16 k = 512 shorts (1 KB), lane-major:
//   n = nt*32 + (lane&31), k = kt*16 + (lane>>5)*8 + e ; tile index t = nt*32 + kt.
// wzr: nt 0..7 = Wz/Uz, nt 8..15 = Wr/Ur. whh: nt 0..7 = Wh/Uh. k<256 -> W, else U.
__global__ void gru_prep(const float* __restrict__ Wz, const float* __restrict__ Uz,
                         const float* __restrict__ Wr, const float* __restrict__ Ur,
                         const float* __restrict__ Wh, const float* __restrict__ Uh,
                         unsigned short* __restrict__ wzr, unsigned short* __restrict__ whh) {
  int idx = blockIdx.x * 256 + threadIdx.x;
  if (idx < 512 * 512) {
    int t = idx >> 9, s = idx & 511, lane = s >> 3, e = s & 7;
    int nt = t >> 5, kt = t & 31;
    int n = nt * 32 + (lane & 31);
    int k = kt * 16 + ((lane >> 5) << 3) + e;
    int nn = n & 255;
    float v;
    if (n < 256) v = (k < 256) ? Wz[k * 256 + nn] : Uz[(k - 256) * 256 + nn];
    else         v = (k < 256) ? Wr[k * 256 + nn] : Ur[(k - 256) * 256 + nn];
    wzr[idx] = f2bf(v);
  } else if (idx < 512 * 512 + 256 * 512) {
    int j = idx - 512 * 512;
    int t = j >> 9, s = j & 511, lane = s >> 3, e = s & 7;
    int nt = t >> 5, kt = t & 31;
    int n = nt * 32 + (lane & 31);
    int k = kt * 16 + ((lane >> 5) << 3) + e;
    float v = (k < 256) ? Wh[k * 256 + n] : Uh[(k - 256) * 256 + n];
    whh[j] = f2bf(v);
  }
}

#define MFMA32(a, b, c) __builtin_amdgcn_mfma_f32_32x32x16_bf16((a), (b), (c), 0, 0, 0)

// ---- FUSED z+r K=512 sweep: 32 chunks; shared A-frags, 4 B-streams, 8 MFMA/chunk ----
// B: ring-4 distance-3 ; A: ring-3 distance-2. Static indices; fenced.
__device__ __forceinline__ void sweep32zr(f16v accz[2][2], f16v accr[2][2],
    const unsigned short* __restrict__ z0p, const unsigned short* __restrict__ z1p,
    const unsigned short* __restrict__ r0p, const unsigned short* __restrict__ r1p,
    const unsigned short* Ax, const unsigned short* Ah, int l31, int hi)
{
  const int r7 = l31 & 7;
  const unsigned short* Ax0 = Ax + l31 * 256;
  const unsigned short* Ax1 = Ax + (32 + l31) * 256;
  const unsigned short* Ah0 = Ah + l31 * 256;
  const unsigned short* Ah1 = Ah + (32 + l31) * 256;
  s8v bz[4][2], br[4][2];
  s8v a[3][2];
#pragma unroll
  for (int i = 0; i < 3; ++i) {
    bz[i][0] = *(const s8v*)(z0p + i * 512);
    bz[i][1] = *(const s8v*)(z1p + i * 512);
    br[i][0] = *(const s8v*)(r0p + i * 512);
    br[i][1] = *(const s8v*)(r1p + i * 512);
  }
  a[0][0] = *(const s8v*)(Ax0 + ((0 + hi) ^ r7) * 8);
  a[0][1] = *(const s8v*)(Ax1 + ((0 + hi) ^ r7) * 8);
  a[1][0] = *(const s8v*)(Ax0 + ((2 + hi) ^ r7) * 8);
  a[1][1] = *(const s8v*)(Ax1 + ((2 + hi) ^ r7) * 8);
#pragma unroll
  for (int c = 0; c < 32; ++c) {
    if (c + 3 < 32) {
      const int s = (c + 3) & 3;
      bz[s][0] = *(const s8v*)(z0p + (c + 3) * 512);
      bz[s][1] = *(const s8v*)(z1p + (c + 3) * 512);
      br[s][0] = *(const s8v*)(r0p + (c + 3) * 512);
      br[s][1] = *(const s8v*)(r1p + (c + 3) * 512);
    }
    if (c + 2 < 32) {
      const int cn = c + 2;
      const int kk = cn & 15;
      const int gp = ((kk * 2 + hi) ^ r7) * 8;
      const int s = cn % 3;
      if (cn < 16) { a[s][0] = *(const s8v*)(Ax0 + gp); a[s][1] = *(const s8v*)(Ax1 + gp); }
      else         { a[s][0] = *(const s8v*)(Ah0 + gp); a[s][1] = *(const s8v*)(Ah1 + gp); }
    }
    __builtin_amdgcn_sched_barrier(0);
    const int sb = c & 3, sa = c % 3;
    accz[0][0] = MFMA32(a[sa][0], bz[sb][0], accz[0][0]);
    accz[0][1] = MFMA32(a[sa][0], bz[sb][1], accz[0][1]);
    accz[1][0] = MFMA32(a[sa][1], bz[sb][0], accz[1][0]);
    accz[1][1] = MFMA32(a[sa][1], bz[sb][1], accz[1][1]);
    accr[0][0] = MFMA32(a[sa][0], br[sb][0], accr[0][0]);
    accr[0][1] = MFMA32(a[sa][0], br[sb][1], accr[0][1]);
    accr[1][0] = MFMA32(a[sa][1], br[sb][0], accr[1][0]);
    accr[1][1] = MFMA32(a[sa][1], br[sb][1], accr[1][1]);
    __builtin_amdgcn_sched_barrier(0);
  }
}

// ---- single-gate K=512 sweep (h pass): v16's form, B ring-6/d-5, A ring-3/d-2 ----
__device__ __forceinline__ void sweep32(f16v acc[2][2],
    const unsigned short* __restrict__ b0p, const unsigned short* __restrict__ b1p,
    const unsigned short* Ax, const unsigned short* Ah, int l31, int hi)
{
  const int r7 = l31 & 7;
  const unsigned short* Ax0 = Ax + l31 * 256;
  const unsigned short* Ax1 = Ax + (32 + l31) * 256;
  const unsigned short* Ah0 = Ah + l31 * 256;
  const unsigned short* Ah1 = Ah + (32 + l31) * 256;
  s8v b[6][2];
  s8v a[3][2];
#pragma unroll
  for (int i = 0; i < 5; ++i) {
    b[i][0] = *(const s8v*)(b0p + i * 512);
    b[i][1] = *(const s8v*)(b1p + i * 512);
  }
  a[0][0] = *(const s8v*)(Ax0 + ((0 + hi) ^ r7) * 8);
  a[0][1] = *(const s8v*)(Ax1 + ((0 + hi) ^ r7) * 8);
  a[1][0] = *(const s8v*)(Ax0 + ((2 + hi) ^ r7) * 8);
  a[1][1] = *(const s8v*)(Ax1 + ((2 + hi) ^ r7) * 8);
#pragma unroll
  for (int c = 0; c < 32; ++c) {
    if (c + 5 < 32) {
      const int s = (c + 5) % 6;
      b[s][0] = *(const s8v*)(b0p + (c + 5) * 512);
      b[s][1] = *(const s8v*)(b1p + (c + 5) * 512);
    }
    if (c + 2 < 32) {
      const int cn = c + 2;
      const int kk = cn & 15;
      const int gp = ((kk * 2 + hi) ^ r7) * 8;
      const int s = cn % 3;
      if (cn < 16) { a[s][0] = *(const s8v*)(Ax0 + gp); a[s][1] = *(const s8v*)(Ax1 + gp); }
      else         { a[s][0] = *(const s8v*)(Ah0 + gp); a[s][1] = *(const s8v*)(Ah1 + gp); }
    }
    __builtin_amdgcn_sched_barrier(0);
    const int sb = c % 6, sa = c % 3;
    acc[0][0] = MFMA32(a[sa][0], b[sb][0], acc[0][0]);
    acc[0][1] = MFMA32(a[sa][0], b[sb][1], acc[0][1]);
    acc[1][0] = MFMA32(a[sa][1], b[sb][0], acc[1][0]);
    acc[1][1] = MFMA32(a[sa][1], b[sb][1], acc[1][1]);
    __builtin_amdgcn_sched_barrier(0);
  }
}

// swizzled scalar LDS accessors (granule-XOR layout)
__device__ __forceinline__ float ldsA_get(const unsigned short* A, int row, int col) {
  int gp = ((col >> 3) ^ (row & 7));
  return bf2f(A[row * 256 + gp * 8 + (col & 7)]);
}
__device__ __forceinline__ void ldsA_put(unsigned short* A, int row, int col, unsigned short v) {
  int gp = ((col >> 3) ^ (row & 7));
  A[row * 256 + gp * 8 + (col & 7)] = v;
}

// C-tile row for reg q (m74/m101 verified): (q&3) + 8*(q>>2) + 4*hi
#define CROW(q, hi) (((q) & 3) + 8 * ((q) >> 2) + 4 * (hi))

// ---------------- main fused kernel: 64 rows per block, 4 waves ----------------
__global__ __launch_bounds__(256, 2) void gru_main(
    const float* __restrict__ x, const float* __restrict__ hp,
    const unsigned short* __restrict__ wzr, const unsigned short* __restrict__ whh,
    const float* __restrict__ bz, const float* __restrict__ br, const float* __restrict__ bh,
    float* __restrict__ out)
{
  __shared__ __align__(16) unsigned short x_l[64 * 256];   // 32 KB; x (bf16, XOR layout)
  __shared__ __align__(16) unsigned short h_l[64 * 256];   // 32 KB; h_prev, later rh

  const int tid = threadIdx.x;
  const int lane = tid & 63;
  const int wv = tid >> 6;                   // 0..3 : wave's 64-col slice
  const int l31 = lane & 31, hi = lane >> 5;
  const int row0 = blockIdx.x * 64;

  // B tile streams (nt stride 16384 shorts = 32 chunks x 512); wave owns nt wv*2, wv*2+1
  const unsigned short* Bz = wzr + (size_t)(wv * 2) * 16384 + lane * 8;
  const unsigned short* Br = wzr + 131072 + (size_t)(wv * 2) * 16384 + lane * 8;
  const unsigned short* Bh = whh + (size_t)(wv * 2) * 16384 + lane * 8;

  // ---- stage x, h tiles to LDS (fp32 -> bf16), granule-XOR layout; 64 elems/thread/array
  {
    const int srow = tid >> 2;               // 0..63
    const int part = tid & 3;                // 64 cols = 8 granules each
    const float* xs = x  + (size_t)(row0 + srow) * 256 + part * 64;
    const float* hs = hp + (size_t)(row0 + srow) * 256 + part * 64;
    unsigned short* xd = x_l + srow * 256;
    unsigned short* hd = h_l + srow * 256;
    const int r7 = srow & 7;
#pragma unroll
    for (int j = 0; j < 8; ++j) {
      int gp = (part * 8 + j) ^ r7;
      f4v v0 = *(const f4v*)(xs + j * 8);
      f4v v1 = *(const f4v*)(xs + j * 8 + 4);
      us8 o;
      o[0]=f2bf(v0[0]); o[1]=f2bf(v0[1]); o[2]=f2bf(v0[2]); o[3]=f2bf(v0[3]);
      o[4]=f2bf(v1[0]); o[5]=f2bf(v1[1]); o[6]=f2bf(v1[2]); o[7]=f2bf(v1[3]);
      *(us8*)(xd + gp * 8) = o;
    }
#pragma unroll
    for (int j = 0; j < 8; ++j) {
      int gp = (part * 8 + j) ^ r7;
      f4v v0 = *(const f4v*)(hs + j * 8);
      f4v v1 = *(const f4v*)(hs + j * 8 + 4);
      us8 o;
      o[0]=f2bf(v0[0]); o[1]=f2bf(v0[1]); o[2]=f2bf(v0[2]); o[3]=f2bf(v0[3]);
      o[4]=f2bf(v1[0]); o[5]=f2bf(v1[1]); o[6]=f2bf(v1[2]); o[7]=f2bf(v1[3]);
      *(us8*)(hd + gp * 8) = o;
    }
  }
  __syncthreads();                           // B1

  f16v accz[2][2], accr[2][2];
  unsigned int zp[2][2][8];                  // z gate, packed bf16 : 32 VGPR

  // ===== FUSED z+r sweep
  accz[0][0] = (f16v)(0.f); accz[0][1] = (f16v)(0.f);
  accz[1][0] = (f16v)(0.f); accz[1][1] = (f16v)(0.f);
  accr[0][0] = (f16v)(0.f); accr[0][1] = (f16v)(0.f);
  accr[1][0] = (f16v)(0.f); accr[1][1] = (f16v)(0.f);
  sweep32zr(accz, accr, Bz, Bz + 16384, Br, Br + 16384, x_l, h_l, l31, hi);

  // ---- z epilogue -> zp regs
#pragma unroll
  for (int fa = 0; fa < 2; ++fa)
#pragma unroll
    for (int fb = 0; fb < 2; ++fb) {
      const int col = wv * 64 + fb * 32 + l31;
      const float bv = bz[col];
#pragma unroll
      for (int qq = 0; qq < 8; ++qq) {
        const int q0 = 2 * qq;
        zp[fa][fb][qq] = pk2(sig_(accz[fa][fb][q0] + bv), sig_(accz[fa][fb][q0 + 1] + bv));
      }
    }

  // ---- r epilogue: rh = r * h_prev -> parked in h_l
  {
    unsigned int rhp[2][2][8];               // transient 32 VGPR (spans one barrier)
#pragma unroll
    for (int fa = 0; fa < 2; ++fa)
#pragma unroll
      for (int fb = 0; fb < 2; ++fb) {
        const int col = wv * 64 + fb * 32 + l31;
        const float bv = br[col];
#pragma unroll
        for (int qq = 0; qq < 8; ++qq) {
          const int q0 = 2 * qq;
          const int r0 = fa * 32 + CROW(q0, hi);
          const float rr0 = sig_(accr[fa][fb][q0]     + bv) * ldsA_get(h_l, r0,     col);
          const float rr1 = sig_(accr[fa][fb][q0 + 1] + bv) * ldsA_get(h_l, r0 + 1, col);
          rhp[fa][fb][qq] = pk2(rr0, rr1);
        }
      }
    __syncthreads();                         // B2: all zr GEMM + epilogue reads of h_l done
#pragma unroll
    for (int fa = 0; fa < 2; ++fa)
#pragma unroll
      for (int fb = 0; fb < 2; ++fb) {
        const int col = wv * 64 + fb * 32 + l31;
#pragma unroll
        for (int qq = 0; qq < 8; ++qq) {
          const int q0 = 2 * qq;
          const int r0 = fa * 32 + CROW(q0, hi);
          const unsigned int w = rhp[fa][fb][qq];
          ldsA_put(h_l, r0,     col, (unsigned short)(w & 0xffffu));
          ldsA_put(h_l, r0 + 1, col, (unsigned short)(w >> 16));
        }
      }
  }
  __syncthreads();                           // B3: rh visible to all waves

  // ===== PASS h: h_hat = tanh(x Wh + rh Uh + bh); h_l now holds rh
  accz[0][0] = (f16v)(0.f); accz[0][1] = (f16v)(0.f);
  accz[1][0] = (f16v)(0.f); accz[1][1] = (f16v)(0.f);
  sweep32(accz, Bh, Bh + 16384, x_l, h_l, l31, hi);

  // ===== final epilogue: h = z*h_prev + (1-z)*h_hat (z from regs, h_prev from global)
#pragma unroll
  for (int fa = 0; fa < 2; ++fa)
#pragma unroll
    for (int fb = 0; fb < 2; ++fb) {
      const int col = wv * 64 + fb * 32 + l31;
      const float bv = bh[col];
#pragma unroll
      for (int qq = 0; qq < 8; ++qq) {
        const int q0 = 2 * qq;
        const int r0 = fa * 32 + CROW(q0, hi);
        const unsigned int zw = zp[fa][fb][qq];
#pragma unroll
        for (int j = 0; j < 2; ++j) {
          const int row = r0 + j;
          const size_t oi = (size_t)(row0 + row) * 256 + col;
          const float hh = tanh_(accz[fa][fb][q0 + j] + bv);
          const float z = bf2f((unsigned short)(j ? (zw >> 16) : (zw & 0xffffu)));
          out[oi] = z * hp[oi] + (1.0f - z) * hh;
        }
      }
    }
}

extern "C" void kernel_launch(void* const* d_in, const int* in_sizes, int n_in,
                              void* d_out, int out_size, void* d_ws, size_t ws_size,
                              hipStream_t stream) {
  const float* x  = (const float*)d_in[0];
  const float* hp = (const float*)d_in[1];
  const float* Wz = (const float*)d_in[2];
  const float* Uz = (const float*)d_in[3];
  const float* bz = (const float*)d_in[4];
  const float* Wr = (const float*)d_in[5];
  const float* Ur = (const float*)d_in[6];
  const float* br = (const float*)d_in[7];
  const float* Wh = (const float*)d_in[8];
  const float* Uh = (const float*)d_in[9];
  const float* bh = (const float*)d_in[10];

  if (ws_size < (size_t)(512 * 512 + 256 * 512) * sizeof(unsigned short)) return;  // need 768 KB

  unsigned short* wzr = (unsigned short*)d_ws;
  unsigned short* whh = wzr + 512 * 512;

  gru_prep<<<1536, 256, 0, stream>>>(Wz, Uz, Wr, Ur, Wh, Uh, wzr, whh);
  gru_main<<<1024, 256, 0, stream>>>(x, hp, wzr, whh, bz, br, bh, (float*)d_out);
}

// Round 20
// 94.880 us; speedup vs baseline: 1.7904x; 1.2055x over previous
//
#include <hip/hip_runtime.h>
#include <hip/hip_bf16.h>

// GRU cell v20: v16 EXACTLY (32x32x16 MFMA, wave tile 64x64, 4 waves/256 thr,
// 64-row tiles, 64 KB LDS, 2 blocks/CU, (256,2), z in regs, rh parks in h_l,
// 3 barriers, fenced rings) with ONE change: fence islands merged pairwise.
// 48 islands of {4 B-loads + 4 A-loads -> 8 independent MFMAs}; B ring-4 and
// A ring-4, pair-prefetch at distance 1 island (~512 cyc > L2 latency).
// Live set ~116 arch regs (down from v16's ~124).

typedef __attribute__((ext_vector_type(8)))  short s8v;            // 8 bf16 = 4 VGPR
typedef __attribute__((ext_vector_type(8)))  unsigned short us8;
typedef __attribute__((ext_vector_type(16))) float f16v;           // 32x32 acc tile
typedef __attribute__((ext_vector_type(4)))  float f4v;

__device__ __forceinline__ float bf2f(unsigned short u) {
  union { unsigned int i; float f; } c; c.i = ((unsigned int)u) << 16; return c.f;
}
__device__ __forceinline__ unsigned short f2bf(float f) {
  __hip_bfloat16 b = __float2bfloat16(f);            // RNE, pairs into v_cvt_pk_bf16_f32
  union { __hip_bfloat16 b; unsigned short u; } c; c.b = b; return c.u;
}
__device__ __forceinline__ unsigned int pk2(float lo, float hi) {
  return (unsigned int)f2bf(lo) | ((unsigned int)f2bf(hi) << 16);
}
__device__ __forceinline__ float sig_(float s)  { return 1.0f / (1.0f + __expf(-s)); }
__device__ __forceinline__ float tanh_(float s) { return 2.0f / (1.0f + __expf(-2.0f * s)) - 1.0f; }

// ---------------- weight prep: fp32 [K][N] -> bf16 32-col fragment tiles ----------------
// Tile (nt, kt) = 32 n x 16 k = 512 shorts (1 KB), lane-major:
//   n = nt*32 + (lane&31), k = kt*16 + (lane>>5)*8 + e ; tile index t = nt*32 + kt.
// wzr: nt 0..7 = Wz/Uz, nt 8..15 = Wr/Ur. whh: nt 0..7 = Wh/Uh. k<256 -> W, else U.
__global__ void gru_prep(const float* __restrict__ Wz, const float* __restrict__ Uz,
                         const float* __restrict__ Wr, const float* __restrict__ Ur,
                         const float* __restrict__ Wh, const float* __restrict__ Uh,
                         unsigned short* __restrict__ wzr, unsigned short* __restrict__ whh) {
  int idx = blockIdx.x * 256 + threadIdx.x;
  if (idx < 512 * 512) {
    int t = idx >> 9, s = idx & 511, lane = s >> 3, e = s & 7;
    int nt = t >> 5, kt = t & 31;
    int n = nt * 32 + (lane & 31);
    int k = kt * 16 + ((lane >> 5) << 3) + e;
    int nn = n & 255;
    float v;
    if (n < 256) v = (k < 256) ? Wz[k * 256 + nn] : Uz[(k - 256) * 256 + nn];
    else         v = (k < 256) ? Wr[k * 256 + nn] : Ur[(k - 256) * 256 + nn];
    wzr[idx] = f2bf(v);
  } else if (idx < 512 * 512 + 256 * 512) {
    int j = idx - 512 * 512;
    int t = j >> 9, s = j & 511, lane = s >> 3, e = s & 7;
    int nt = t >> 5, kt = t & 31;
    int n = nt * 32 + (lane & 31);
    int k = kt * 16 + ((lane >> 5) << 3) + e;
    float v = (k < 256) ? Wh[k * 256 + n] : Uh[(k - 256) * 256 + n];
    whh[j] = f2bf(v);
  }
}

#define MFMA32(a, b, c) __builtin_amdgcn_mfma_f32_32x32x16_bf16((a), (b), (c), 0, 0, 0)

// ---- K=512 sweep: 32 chunks of 16 in 16 pair-islands; A = x_l (c<16) then h_l ----
// B ring-4 + A ring-4, pair prefetch at distance 1 island. Static indices; fenced.
__device__ __forceinline__ void sweep32(f16v acc[2][2],
    const unsigned short* __restrict__ b0p, const unsigned short* __restrict__ b1p,
    const unsigned short* Ax, const unsigned short* Ah, int l31, int hi)
{
  const int r7 = l31 & 7;                    // rows l31 and 32+l31 share (row&7)
  const unsigned short* Ax0 = Ax + l31 * 256;
  const unsigned short* Ax1 = Ax + (32 + l31) * 256;
  const unsigned short* Ah0 = Ah + l31 * 256;
  const unsigned short* Ah1 = Ah + (32 + l31) * 256;
  s8v b[4][2];
  s8v a[4][2];
  // prologue: chunks 0,1
#pragma unroll
  for (int i = 0; i < 2; ++i) {
    b[i][0] = *(const s8v*)(b0p + i * 512);
    b[i][1] = *(const s8v*)(b1p + i * 512);
    const int gp = ((i * 2 + hi) ^ r7) * 8;
    a[i][0] = *(const s8v*)(Ax0 + gp);
    a[i][1] = *(const s8v*)(Ax1 + gp);
  }
#pragma unroll
  for (int c = 0; c < 32; c += 2) {
    if (c + 2 < 32) {
#pragma unroll
      for (int j = 0; j < 2; ++j) {
        const int cn = c + 2 + j;
        const int s = cn & 3;
        b[s][0] = *(const s8v*)(b0p + cn * 512);
        b[s][1] = *(const s8v*)(b1p + cn * 512);
        const int kk = cn & 15;
        const int gp = ((kk * 2 + hi) ^ r7) * 8;
        if (cn < 16) { a[s][0] = *(const s8v*)(Ax0 + gp); a[s][1] = *(const s8v*)(Ax1 + gp); }
        else         { a[s][0] = *(const s8v*)(Ah0 + gp); a[s][1] = *(const s8v*)(Ah1 + gp); }
      }
    }
    __builtin_amdgcn_sched_barrier(0);
#pragma unroll
    for (int j = 0; j < 2; ++j) {
      const int s = (c + j) & 3;
      acc[0][0] = MFMA32(a[s][0], b[s][0], acc[0][0]);
      acc[0][1] = MFMA32(a[s][0], b[s][1], acc[0][1]);
      acc[1][0] = MFMA32(a[s][1], b[s][0], acc[1][0]);
      acc[1][1] = MFMA32(a[s][1], b[s][1], acc[1][1]);
    }
    __builtin_amdgcn_sched_barrier(0);
  }
}

// swizzled scalar LDS accessors (granule-XOR layout)
__device__ __forceinline__ float ldsA_get(const unsigned short* A, int row, int col) {
  int gp = ((col >> 3) ^ (row & 7));
  return bf2f(A[row * 256 + gp * 8 + (col & 7)]);
}
__device__ __forceinline__ void ldsA_put(unsigned short* A, int row, int col, unsigned short v) {
  int gp = ((col >> 3) ^ (row & 7));
  A[row * 256 + gp * 8 + (col & 7)] = v;
}

// C-tile row for reg q (m74/m101 verified): (q&3) + 8*(q>>2) + 4*hi
#define CROW(q, hi) (((q) & 3) + 8 * ((q) >> 2) + 4 * (hi))

// ---------------- main fused kernel: 64 rows per block, 4 waves ----------------
__global__ __launch_bounds__(256, 2) void gru_main(
    const float* __restrict__ x, const float* __restrict__ hp,
    const unsigned short* __restrict__ wzr, const unsigned short* __restrict__ whh,
    const float* __restrict__ bz, const float* __restrict__ br, const float* __restrict__ bh,
    float* __restrict__ out)
{
  __shared__ __align__(16) unsigned short x_l[64 * 256];   // 32 KB; x (bf16, XOR layout)
  __shared__ __align__(16) unsigned short h_l[64 * 256];   // 32 KB; h_prev, later rh

  const int tid = threadIdx.x;
  const int lane = tid & 63;
  const int wv = tid >> 6;                   // 0..3 : wave's 64-col slice
  const int l31 = lane & 31, hi = lane >> 5;
  const int row0 = blockIdx.x * 64;

  // B tile streams (nt stride 16384 shorts = 32 chunks x 512); wave owns nt wv*2, wv*2+1
  const unsigned short* Bz = wzr + (size_t)(wv * 2) * 16384 + lane * 8;
  const unsigned short* Br = wzr + 131072 + (size_t)(wv * 2) * 16384 + lane * 8;
  const unsigned short* Bh = whh + (size_t)(wv * 2) * 16384 + lane * 8;

  // ---- stage x, h tiles to LDS (fp32 -> bf16), granule-XOR layout; 64 elems/thread/array
  {
    const int srow = tid >> 2;               // 0..63
    const int part = tid & 3;                // 64 cols = 8 granules each
    const float* xs = x  + (size_t)(row0 + srow) * 256 + part * 64;
    const float* hs = hp + (size_t)(row0 + srow) * 256 + part * 64;
    unsigned short* xd = x_l + srow * 256;
    unsigned short* hd = h_l + srow * 256;
    const int r7 = srow & 7;
#pragma unroll
    for (int j = 0; j < 8; ++j) {
      int gp = (part * 8 + j) ^ r7;
      f4v v0 = *(const f4v*)(xs + j * 8);
      f4v v1 = *(const f4v*)(xs + j * 8 + 4);
      us8 o;
      o[0]=f2bf(v0[0]); o[1]=f2bf(v0[1]); o[2]=f2bf(v0[2]); o[3]=f2bf(v0[3]);
      o[4]=f2bf(v1[0]); o[5]=f2bf(v1[1]); o[6]=f2bf(v1[2]); o[7]=f2bf(v1[3]);
      *(us8*)(xd + gp * 8) = o;
    }
#pragma unroll
    for (int j = 0; j < 8; ++j) {
      int gp = (part * 8 + j) ^ r7;
      f4v v0 = *(const f4v*)(hs + j * 8);
      f4v v1 = *(const f4v*)(hs + j * 8 + 4);
      us8 o;
      o[0]=f2bf(v0[0]); o[1]=f2bf(v0[1]); o[2]=f2bf(v0[2]); o[3]=f2bf(v0[3]);
      o[4]=f2bf(v1[0]); o[5]=f2bf(v1[1]); o[6]=f2bf(v1[2]); o[7]=f2bf(v1[3]);
      *(us8*)(hd + gp * 8) = o;
    }
  }
  __syncthreads();                           // B1

  f16v acc[2][2];
  unsigned int zp[2][2][8];                  // z gate, packed bf16 : 32 VGPR

  // ===== PASS z: z = sigmoid(x Wz + h Uz + bz) -> zp (registers)
  acc[0][0] = (f16v)(0.f); acc[0][1] = (f16v)(0.f);
  acc[1][0] = (f16v)(0.f); acc[1][1] = (f16v)(0.f);
  sweep32(acc, Bz, Bz + 16384, x_l, h_l, l31, hi);
#pragma unroll
  for (int fa = 0; fa < 2; ++fa)
#pragma unroll
    for (int fb = 0; fb < 2; ++fb) {
      const int col = wv * 64 + fb * 32 + l31;
      const float bv = bz[col];
#pragma unroll
      for (int qq = 0; qq < 8; ++qq) {
        const int q0 = 2 * qq;
        zp[fa][fb][qq] = pk2(sig_(acc[fa][fb][q0] + bv), sig_(acc[fa][fb][q0 + 1] + bv));
      }
    }

  // ===== PASS r: r = sigmoid(x Wr + h Ur + br); rh = r * h_prev -> parked in h_l
  acc[0][0] = (f16v)(0.f); acc[0][1] = (f16v)(0.f);
  acc[1][0] = (f16v)(0.f); acc[1][1] = (f16v)(0.f);
  sweep32(acc, Br, Br + 16384, x_l, h_l, l31, hi);
  {
    unsigned int rhp[2][2][8];               // transient 32 VGPR (spans one barrier)
#pragma unroll
    for (int fa = 0; fa < 2; ++fa)
#pragma unroll
      for (int fb = 0; fb < 2; ++fb) {
        const int col = wv * 64 + fb * 32 + l31;
        const float bv = br[col];
#pragma unroll
        for (int qq = 0; qq < 8; ++qq) {
          const int q0 = 2 * qq;
          const int r0 = fa * 32 + CROW(q0, hi);
          const float rr0 = sig_(acc[fa][fb][q0]     + bv) * ldsA_get(h_l, r0,     col);
          const float rr1 = sig_(acc[fa][fb][q0 + 1] + bv) * ldsA_get(h_l, r0 + 1, col);
          rhp[fa][fb][qq] = pk2(rr0, rr1);
        }
      }
    __syncthreads();                         // B2: all z/r GEMM + epilogue reads of h_l done
#pragma unroll
    for (int fa = 0; fa < 2; ++fa)
#pragma unroll
      for (int fb = 0; fb < 2; ++fb) {
        const int col = wv * 64 + fb * 32 + l31;
#pragma unroll
        for (int qq = 0; qq < 8; ++qq) {
          const int q0 = 2 * qq;
          const int r0 = fa * 32 + CROW(q0, hi);
          const unsigned int w = rhp[fa][fb][qq];
          ldsA_put(h_l, r0,     col, (unsigned short)(w & 0xffffu));
          ldsA_put(h_l, r0 + 1, col, (unsigned short)(w >> 16));
        }
      }
  }
  __syncthreads();                           // B3: rh visible to all waves

  // ===== PASS h: h_hat = tanh(x Wh + rh Uh + bh); h_l now holds rh
  acc[0][0] = (f16v)(0.f); acc[0][1] = (f16v)(0.f);
  acc[1][0] = (f16v)(0.f); acc[1][1] = (f16v)(0.f);
  sweep32(acc, Bh, Bh + 16384, x_l, h_l, l31, hi);

  // ===== final epilogue: h = z*h_prev + (1-z)*h_hat (z from regs, h_prev from global)
#pragma unroll
  for (int fa = 0; fa < 2; ++fa)
#pragma unroll
    for (int fb = 0; fb < 2; ++fb) {
      const int col = wv * 64 + fb * 32 + l31;
      const float bv = bh[col];
#pragma unroll
      for (int qq = 0; qq < 8; ++qq) {
        const int q0 = 2 * qq;
        const int r0 = fa * 32 + CROW(q0, hi);
        const unsigned int zw = zp[fa][fb][qq];
#pragma unroll
        for (int j = 0; j < 2; ++j) {
          const int row = r0 + j;
          const size_t oi = (size_t)(row0 + row) * 256 + col;
          const float hh = tanh_(acc[fa][fb][q0 + j] + bv);
          const float z = bf2f((unsigned short)(j ? (zw >> 16) : (zw & 0xffffu)));
          out[oi] = z * hp[oi] + (1.0f - z) * hh;
        }
      }
    }
}

extern "C" void kernel_launch(void* const* d_in, const int* in_sizes, int n_in,
                              void* d_out, int out_size, void* d_ws, size_t ws_size,
                              hipStream_t stream) {
  const float* x  = (const float*)d_in[0];
  const float* hp = (const float*)d_in[1];
  const float* Wz = (const float*)d_in[2];
  const float* Uz = (const float*)d_in[3];
  const float* bz = (const float*)d_in[4];
  const float* Wr = (const float*)d_in[5];
  const float* Ur = (const float*)d_in[6];
  const float* br = (const float*)d_in[7];
  const float* Wh = (const float*)d_in[8];
  const float* Uh = (const float*)d_in[9];
  const float* bh = (const float*)d_in[10];

  if (ws_size < (size_t)(512 * 512 + 256 * 512) * sizeof(unsigned short)) return;  // need 768 KB

  unsigned short* wzr = (unsigned short*)d_ws;
  unsigned short* whh = wzr + 512 * 512;

  gru_prep<<<1536, 256, 0, stream>>>(Wz, Uz, Wr, Ur, Wh, Uh, wzr, whh);
  gru_main<<<1024, 256, 0, stream>>>(x, hp, wzr, whh, bz, br, bh, (float*)d_out);
}